// Round 6
// baseline (17985.991 us; speedup 1.0000x reference)
//
#include <hip/hip_runtime.h>
#include <hip/hip_bf16.h>

#define TT 512
#define BB 64
#define DD 2048
#define LL 4
#define VV 64

typedef unsigned short u16;
typedef unsigned int u32;
typedef unsigned long long u64;
typedef __attribute__((ext_vector_type(8))) short s16x8;
typedef __attribute__((ext_vector_type(4))) float f32x4;

#define MFMA(a, b, c) __builtin_amdgcn_mfma_f32_16x16x32_bf16((a), (b), (c), 0, 0, 0)

__device__ inline u16 f2b(float f) {
  u32 u = __builtin_bit_cast(u32, f);
  u32 r = (u + 0x7fffu + ((u >> 16) & 1u)) >> 16;
  return (u16)r;
}
__device__ inline float b2f(u16 b) {
  u32 u = ((u32)b) << 16;
  return __builtin_bit_cast(float, u);
}

__global__ __launch_bounds__(256) void convert_w(const float* __restrict__ src,
                                                 u16* __restrict__ dst, size_t n4) {
  size_t i = (size_t)blockIdx.x * 256 + threadIdx.x;
  size_t stride = (size_t)gridDim.x * 256;
  for (size_t j = i; j < n4; j += stride) {
    float4 f = ((const float4*)src)[j];
    ushort4 o;
    o.x = f2b(f.x); o.y = f2b(f.y); o.z = f2b(f.z); o.w = f2b(f.w);
    ((ushort4*)dst)[j] = o;
  }
}

// WoutT[v][k] = bf16(Wout[k][v]);  Wout is [2048][64] fp32
__global__ __launch_bounds__(256) void convert_woT(const float* __restrict__ Wout,
                                                   u16* __restrict__ WoT) {
  int g = blockIdx.x * 256 + threadIdx.x;  // 131072 total
  int v = g >> 11, k = g & 2047;
  WoT[(size_t)v * DD + k] = f2b(Wout[(size_t)k * VV + v]);
}

// Persistent kernel: 256 blocks x 512 threads, 1 block/CU.
// Block bid -> layer l = bid>>6, columns col0 = (bid&63)*32.
// Weights pinned in registers via opaque asm (32 x s16x8 = 128 regs/lane).
// State stores write-through (SYSTEM-scope relaxed). Grid barrier is
// zero-RMW: per-block flag line (128B apart) + every block scans all 256
// flags in one parallel load round (8 waves x 32 flags). One ACQUIRE inv
// per block per step for state visibility.
__global__ __launch_bounds__(512, 2)
void persist(const int* __restrict__ ids, const int* __restrict__ slen,
             const float* __restrict__ bxp, const float* __restrict__ bhp,
             const u16* __restrict__ embb,
             const u16* __restrict__ Wxb, const u16* __restrict__ Whb,
             const u16* __restrict__ WoT, const float* __restrict__ bout,
             u16* b0, u16* b1, u16* b2,
             float* __restrict__ out, int* flags) {
  const int tid = threadIdx.x, bid = blockIdx.x;
  const int l = bid >> 6;
  const int col0 = (bid & 63) << 5;
  const int w = tid >> 6, lane = tid & 63;
  const int ch = w & 1, ks = w >> 1;
  const int lr = lane & 15, q = lane >> 4;
  const int ncol = col0 + (ch << 4) + lr;
  const int kb0 = (ks << 9) + (q << 3);  // ks*512 + q*8

  // ---- load weight fragments (once), pin as opaque ----
  s16x8 wx[16], wh[16];
  {
    const u16* p0 = Wxb + ((size_t)l * DD + ncol) * DD + kb0;
    const u16* p1 = Whb + ((size_t)l * DD + ncol) * DD + kb0;
#pragma unroll
    for (int kt = 0; kt < 16; ++kt) {
      wx[kt] = *(const s16x8*)(p0 + (kt << 5));
      wh[kt] = *(const s16x8*)(p1 + (kt << 5));
    }
  }
#pragma unroll
  for (int kt = 0; kt < 16; ++kt) {
    asm("" : "+v"(wx[kt]));
    asm("" : "+v"(wh[kt]));
  }

  // ---- out-proj assignment: 4 batch rows x 4 vocab cols per block ----
  const int opo = tid >> 5, ln32 = tid & 31;
  const int opb = ((bid >> 4) << 2) + (opo >> 2);
  const int opv = ((bid & 15) << 2) + (opo & 3);
  const float boutv = bout[opv];

  // ---- reduce-quad mapping: each thread owns 4 adjacent cols of one row ----
  const int cch = tid >> 8;            // 0/1: 16-col half
  const int qm = (tid >> 2) & 63;      // batch row
  const int nq = (tid & 3) << 2;       // col-quad within half
  const int qcol = col0 + (cch << 4) + nq;
  float qb[4];
#pragma unroll
  for (int e = 0; e < 4; ++e)
    qb[e] = bxp[l * DD + qcol + e] + bhp[l * DD + qcol + e];
  const int qlen = slen[qm];

  // barrier sweep assignment: wave w scans flags [w*32 .. w*32+31]
  const int fidx = ((w << 5) + (lane & 31)) << 5;  // x32 ints = 128 B spacing

  __shared__ __align__(16) float part[8][64][20];
  __shared__ int sids[64];
  __shared__ int wok[8];
  __shared__ int alldone;

  const u16* Hp = b2;  // read buffer (state t-1); b2 zeroed = H0
  u16* Hc = b0;        // write buffer (state t)
  u16* Ho = b1;        // oldest, next write target

  for (int t = 0; t <= TT; ++t) {
    if (t < TT) {
      if (tid < BB) sids[tid] = ids[tid * TT + t];
      __syncthreads();

      const u16* hsrc = Hp + (size_t)l * BB * DD;
      const u16 *xs0, *xs1, *xs2, *xs3;
      if (l == 0) {
        xs0 = embb + (size_t)sids[lr] * DD;
        xs1 = embb + (size_t)sids[lr + 16] * DD;
        xs2 = embb + (size_t)sids[lr + 32] * DD;
        xs3 = embb + (size_t)sids[lr + 48] * DD;
      } else {
        const u16* xsrc = Hp + (size_t)(l - 1) * BB * DD;
        xs0 = xsrc + (size_t)lr * DD;
        xs1 = xsrc + (size_t)(lr + 16) * DD;
        xs2 = xsrc + (size_t)(lr + 32) * DD;
        xs3 = xsrc + (size_t)(lr + 48) * DD;
      }
      const u16* hs0 = hsrc + (size_t)lr * DD;
      const u16* hs1 = hsrc + (size_t)(lr + 16) * DD;
      const u16* hs2 = hsrc + (size_t)(lr + 32) * DD;
      const u16* hs3 = hsrc + (size_t)(lr + 48) * DD;

      f32x4 acc0 = {0, 0, 0, 0}, acc1 = {0, 0, 0, 0};
      f32x4 acc2 = {0, 0, 0, 0}, acc3 = {0, 0, 0, 0};
#pragma unroll
      for (int kt = 0; kt < 16; ++kt) {
        const int kk = kb0 + (kt << 5);
        s16x8 ax0 = *(const s16x8*)(xs0 + kk);
        s16x8 ax1 = *(const s16x8*)(xs1 + kk);
        s16x8 ax2 = *(const s16x8*)(xs2 + kk);
        s16x8 ax3 = *(const s16x8*)(xs3 + kk);
        s16x8 ah0 = *(const s16x8*)(hs0 + kk);
        s16x8 ah1 = *(const s16x8*)(hs1 + kk);
        s16x8 ah2 = *(const s16x8*)(hs2 + kk);
        s16x8 ah3 = *(const s16x8*)(hs3 + kk);
        acc0 = MFMA(ax0, wx[kt], acc0); acc0 = MFMA(ah0, wh[kt], acc0);
        acc1 = MFMA(ax1, wx[kt], acc1); acc1 = MFMA(ah1, wh[kt], acc1);
        acc2 = MFMA(ax2, wx[kt], acc2); acc2 = MFMA(ah2, wh[kt], acc2);
        acc3 = MFMA(ax3, wx[kt], acc3); acc3 = MFMA(ah3, wh[kt], acc3);
      }
#pragma unroll
      for (int i = 0; i < 4; ++i) {
        part[w][(q << 2) + i][lr] = acc0[i];
        part[w][16 + (q << 2) + i][lr] = acc1[i];
        part[w][32 + (q << 2) + i][lr] = acc2[i];
        part[w][48 + (q << 2) + i][lr] = acc3[i];
      }
      __syncthreads();
      // k-reduce quad + bias + tanh + mask + packed write-through store
      {
        f32x4 p0 = *(const f32x4*)&part[cch][qm][nq];
        f32x4 p1 = *(const f32x4*)&part[cch + 2][qm][nq];
        f32x4 p2 = *(const f32x4*)&part[cch + 4][qm][nq];
        f32x4 p3 = *(const f32x4*)&part[cch + 6][qm][nq];
        f32x4 sum = ((p0 + p1) + p2) + p3;
        float h0 = tanhf(sum[0] + qb[0]);
        float h1 = tanhf(sum[1] + qb[1]);
        float h2 = tanhf(sum[2] + qb[2]);
        float h3 = tanhf(sum[3] + qb[3]);
        size_t idx = ((size_t)l * BB + qm) * DD + qcol;
        u64 pk = (u64)f2b(h0) | ((u64)f2b(h1) << 16) |
                 ((u64)f2b(h2) << 32) | ((u64)f2b(h3) << 48);
        u64 val = (t < qlen) ? pk : *(const u64*)(Hp + idx);
        __hip_atomic_store((u64*)(Hc + idx), val, __ATOMIC_RELAXED,
                           __HIP_MEMORY_SCOPE_SYSTEM);
      }
      asm volatile("s_waitcnt vmcnt(0)" ::: "memory");  // stores at coherence pt
    }
    __syncthreads();  // all waves' stores drained

    const int ep = t + 1;
    // barrier arrival: one plain bypass store to our own flag line (no RMW)
    if (t < TT && tid == 0)
      __hip_atomic_store(&flags[bid << 5], ep, __ATOMIC_RELAXED,
                         __HIP_MEMORY_SCOPE_SYSTEM);

    // output projection for step t-1 (reads Hp; safe under triple-buffering,
    // overlapped with other blocks' arrivals)
    if (t > 0) {
      const u16* h3p = Hp + (size_t)3 * BB * DD;
      const u16* hp = h3p + (size_t)opb * DD + (ln32 << 6);
      const u16* wp = WoT + (size_t)opv * DD + (ln32 << 6);
      float sacc = 0.f;
#pragma unroll
      for (int j = 0; j < 64; j += 8) {
        s16x8 hv8 = *(const s16x8*)(hp + j);
        s16x8 wv8 = *(const s16x8*)(wp + j);
#pragma unroll
        for (int e = 0; e < 8; ++e)
          sacc = fmaf(b2f((u16)hv8[e]), b2f((u16)wv8[e]), sacc);
      }
#pragma unroll
      for (int d = 16; d > 0; d >>= 1) sacc += __shfl_xor(sacc, d, 64);
      if (ln32 == 0)
        out[((size_t)opb * TT + (t - 1)) * VV + opv] = sacc + boutv;
    }

    // barrier wait: every block scans all 256 flags (parallel load round)
    if (t < TT) {
      for (;;) {
        int f = ep;
        if (lane < 32)
          f = __hip_atomic_load(&flags[fidx], __ATOMIC_RELAXED,
                                __HIP_MEMORY_SCOPE_SYSTEM);
        int ok = __all(f - ep >= 0);
        if (lane == 0) wok[w] = ok;
        __syncthreads();
        if (tid == 0)
          alldone = wok[0] & wok[1] & wok[2] & wok[3] &
                    wok[4] & wok[5] & wok[6] & wok[7];
        __syncthreads();
        if (alldone) break;
        __builtin_amdgcn_s_sleep(1);
      }
      if (tid == 0)  // acquire: invalidate L1/L2 so remote state is visible
        __hip_atomic_load(&flags[0], __ATOMIC_ACQUIRE, __HIP_MEMORY_SCOPE_AGENT);
      __syncthreads();
      const u16* newHp = Hc;
      u16* newHc = Ho;
      Ho = (u16*)Hp;
      Hp = newHp;
      Hc = newHc;
    }
  }
}

extern "C" void kernel_launch(void* const* d_in, const int* in_sizes, int n_in,
                              void* d_out, int out_size, void* d_ws, size_t ws_size,
                              hipStream_t stream) {
  const int* ids = (const int*)d_in[0];
  const int* slen = (const int*)d_in[1];
  const float* emb = (const float*)d_in[2];
  const float* Wx = (const float*)d_in[3];
  const float* bx = (const float*)d_in[4];
  const float* Wh = (const float*)d_in[5];
  const float* bh = (const float*)d_in[6];
  const float* Wout = (const float*)d_in[7];
  const float* bout = (const float*)d_in[8];
  float* out = (float*)d_out;

  char* ws = (char*)d_ws;
  const size_t oW = (size_t)LL * DD * DD * 2;   // 33,554,432 B per weight array
  const size_t oWoT = (size_t)VV * DD * 2;      // 262,144 B
  const size_t oEmb = (size_t)VV * DD * 2;      // 262,144 B
  const size_t oHb = (size_t)LL * BB * DD * 2;  // 1,048,576 B
  u16* Wxb = (u16*)ws;
  u16* Whb = (u16*)(ws + oW);
  u16* WoT = (u16*)(ws + 2 * oW);
  u16* embb = (u16*)(ws + 2 * oW + oWoT);
  u16* b0 = (u16*)(ws + 2 * oW + oWoT + oEmb);
  u16* b1 = (u16*)(ws + 2 * oW + oWoT + oEmb + oHb);
  u16* b2 = (u16*)(ws + 2 * oW + oWoT + oEmb + 2 * oHb);
  int* flags = (int*)(ws + 2 * oW + oWoT + oEmb + 3 * oHb);

  // zero state buffers + flag lines (graph replay re-runs this)
  hipMemsetAsync(ws + 2 * oW + oWoT + oEmb, 0, 3 * oHb + 32768, stream);

  const size_t n4 = (size_t)LL * DD * DD / 4;
  convert_w<<<dim3(4096), dim3(256), 0, stream>>>(Wx, Wxb, n4);
  convert_w<<<dim3(4096), dim3(256), 0, stream>>>(Wh, Whb, n4);
  convert_w<<<dim3(128), dim3(256), 0, stream>>>(emb, embb, (size_t)VV * DD / 4);
  convert_woT<<<dim3(512), dim3(256), 0, stream>>>(Wout, WoT);

  void* kp[14];
  kp[0] = (void*)&ids;  kp[1] = (void*)&slen;
  kp[2] = (void*)&bx;   kp[3] = (void*)&bh;   kp[4] = (void*)&embb;
  kp[5] = (void*)&Wxb;  kp[6] = (void*)&Whb;  kp[7] = (void*)&WoT;
  kp[8] = (void*)&bout; kp[9] = (void*)&b0;   kp[10] = (void*)&b1;
  kp[11] = (void*)&b2;  kp[12] = (void*)&out; kp[13] = (void*)&flags;
  hipLaunchCooperativeKernel((const void*)persist, dim3(256), dim3(512), kp, 0, stream);
}

// Round 7
// 17631.772 us; speedup vs baseline: 1.0201x; 1.0201x over previous
//
#include <hip/hip_runtime.h>
#include <hip/hip_bf16.h>

#define TT 512
#define BB 64
#define DD 2048
#define LL 4
#define VV 64

typedef unsigned short u16;
typedef unsigned int u32;
typedef unsigned long long u64;
typedef __attribute__((ext_vector_type(8))) short s16x8;
typedef __attribute__((ext_vector_type(4))) float f32x4;

#define MFMA(a, b, c) __builtin_amdgcn_mfma_f32_16x16x32_bf16((a), (b), (c), 0, 0, 0)

__device__ inline u16 f2b(float f) {
  u32 u = __builtin_bit_cast(u32, f);
  u32 r = (u + 0x7fffu + ((u >> 16) & 1u)) >> 16;
  return (u16)r;
}
__device__ inline float b2f(u16 b) {
  u32 u = ((u32)b) << 16;
  return __builtin_bit_cast(float, u);
}

__global__ __launch_bounds__(256) void convert_w(const float* __restrict__ src,
                                                 u16* __restrict__ dst, size_t n4) {
  size_t i = (size_t)blockIdx.x * 256 + threadIdx.x;
  size_t stride = (size_t)gridDim.x * 256;
  for (size_t j = i; j < n4; j += stride) {
    float4 f = ((const float4*)src)[j];
    ushort4 o;
    o.x = f2b(f.x); o.y = f2b(f.y); o.z = f2b(f.z); o.w = f2b(f.w);
    ((ushort4*)dst)[j] = o;
  }
}

// WoutT[v][k] = bf16(Wout[k][v]);  Wout is [2048][64] fp32
__global__ __launch_bounds__(256) void convert_woT(const float* __restrict__ Wout,
                                                   u16* __restrict__ WoT) {
  int g = blockIdx.x * 256 + threadIdx.x;  // 131072 total
  int v = g >> 11, k = g & 2047;
  WoT[(size_t)v * DD + k] = f2b(Wout[(size_t)k * VV + v]);
}

// Persistent kernel: 256 blocks x 512 threads, 1 block/CU.
// Block bid -> layer l = bid>>6, columns col0 = (bid&63)*32.
// Weights pinned in registers via opaque asm (32 x s16x8 = 128 regs/lane).
// State stores write-through (SYSTEM-scope relaxed) to a RING OF 4 buffers;
// stale-hit hazard on address reuse (period 4) is covered by ONE L1/L2
// acquire-invalidate every 4 steps (any 4-step reuse window contains exactly
// one inv) -> 3 of 4 steps run on warm caches. Barrier: zero-RMW flag
// store + all-block parallel scan (SYSTEM bypass loads, never cached).
__global__ __launch_bounds__(512, 2)
void persist(const int* __restrict__ ids, const int* __restrict__ slen,
             const float* __restrict__ bxp, const float* __restrict__ bhp,
             const u16* __restrict__ embb,
             const u16* __restrict__ Wxb, const u16* __restrict__ Whb,
             const u16* __restrict__ WoT, const float* __restrict__ bout,
             u16* hb, float* __restrict__ out, int* flags) {
  const int tid = threadIdx.x, bid = blockIdx.x;
  const int l = bid >> 6;
  const int col0 = (bid & 63) << 5;
  const int w = tid >> 6, lane = tid & 63;
  const int ch = w & 1, ks = w >> 1;
  const int lr = lane & 15, q = lane >> 4;
  const int ncol = col0 + (ch << 4) + lr;
  const int kb0 = (ks << 9) + (q << 3);  // ks*512 + q*8
  const size_t HSZ = (size_t)LL * BB * DD;  // elements per state buffer

  // ---- load weight fragments (once), pin as opaque ----
  s16x8 wx[16], wh[16];
  {
    const u16* p0 = Wxb + ((size_t)l * DD + ncol) * DD + kb0;
    const u16* p1 = Whb + ((size_t)l * DD + ncol) * DD + kb0;
#pragma unroll
    for (int kt = 0; kt < 16; ++kt) {
      wx[kt] = *(const s16x8*)(p0 + (kt << 5));
      wh[kt] = *(const s16x8*)(p1 + (kt << 5));
    }
  }
#pragma unroll
  for (int kt = 0; kt < 16; ++kt) {
    asm("" : "+v"(wx[kt]));
    asm("" : "+v"(wh[kt]));
  }

  // ---- out-proj assignment: 4 batch rows x 4 vocab cols per block ----
  const int opo = tid >> 5, ln32 = tid & 31;
  const int opb = ((bid >> 4) << 2) + (opo >> 2);
  const int opv = ((bid & 15) << 2) + (opo & 3);
  const float boutv = bout[opv];

  // ---- reduce-quad mapping: each thread owns 4 adjacent cols of one row ----
  const int cch = tid >> 8;            // 0/1: 16-col half
  const int qm = (tid >> 2) & 63;      // batch row
  const int nq = (tid & 3) << 2;       // col-quad within half
  const int qcol = col0 + (cch << 4) + nq;
  float qb[4];
#pragma unroll
  for (int e = 0; e < 4; ++e)
    qb[e] = bxp[l * DD + qcol + e] + bhp[l * DD + qcol + e];
  const int qlen = slen[qm];

  // barrier sweep assignment: wave w scans flags [w*32 .. w*32+31]
  const int fidx = ((w << 5) + (lane & 31)) << 5;  // x32 ints = 128 B spacing

  __shared__ __align__(16) float part[8][64][20];
  __shared__ int sids[64];
  __shared__ int wok[8];
  __shared__ int alldone;

  for (int t = 0; t <= TT; ++t) {
    // ring: state(t) lives in buffer (t & 3); state(-1) = buffer 3 (zeroed)
    const u16* Hp = hb + (size_t)((t + 3) & 3) * HSZ;
    u16* Hc = hb + (size_t)(t & 3) * HSZ;

    if (t < TT) {
      if (tid < BB) sids[tid] = ids[tid * TT + t];
      __syncthreads();

      const u16* hsrc = Hp + (size_t)l * BB * DD;
      const u16 *xs0, *xs1, *xs2, *xs3;
      if (l == 0) {
        xs0 = embb + (size_t)sids[lr] * DD;
        xs1 = embb + (size_t)sids[lr + 16] * DD;
        xs2 = embb + (size_t)sids[lr + 32] * DD;
        xs3 = embb + (size_t)sids[lr + 48] * DD;
      } else {
        const u16* xsrc = Hp + (size_t)(l - 1) * BB * DD;
        xs0 = xsrc + (size_t)lr * DD;
        xs1 = xsrc + (size_t)(lr + 16) * DD;
        xs2 = xsrc + (size_t)(lr + 32) * DD;
        xs3 = xsrc + (size_t)(lr + 48) * DD;
      }
      const u16* hs0 = hsrc + (size_t)lr * DD;
      const u16* hs1 = hsrc + (size_t)(lr + 16) * DD;
      const u16* hs2 = hsrc + (size_t)(lr + 32) * DD;
      const u16* hs3 = hsrc + (size_t)(lr + 48) * DD;

      f32x4 acc0 = {0, 0, 0, 0}, acc1 = {0, 0, 0, 0};
      f32x4 acc2 = {0, 0, 0, 0}, acc3 = {0, 0, 0, 0};
#pragma unroll
      for (int kt = 0; kt < 16; ++kt) {
        const int kk = kb0 + (kt << 5);
        s16x8 ax0 = *(const s16x8*)(xs0 + kk);
        s16x8 ax1 = *(const s16x8*)(xs1 + kk);
        s16x8 ax2 = *(const s16x8*)(xs2 + kk);
        s16x8 ax3 = *(const s16x8*)(xs3 + kk);
        s16x8 ah0 = *(const s16x8*)(hs0 + kk);
        s16x8 ah1 = *(const s16x8*)(hs1 + kk);
        s16x8 ah2 = *(const s16x8*)(hs2 + kk);
        s16x8 ah3 = *(const s16x8*)(hs3 + kk);
        acc0 = MFMA(ax0, wx[kt], acc0); acc0 = MFMA(ah0, wh[kt], acc0);
        acc1 = MFMA(ax1, wx[kt], acc1); acc1 = MFMA(ah1, wh[kt], acc1);
        acc2 = MFMA(ax2, wx[kt], acc2); acc2 = MFMA(ah2, wh[kt], acc2);
        acc3 = MFMA(ax3, wx[kt], acc3); acc3 = MFMA(ah3, wh[kt], acc3);
      }
#pragma unroll
      for (int i = 0; i < 4; ++i) {
        part[w][(q << 2) + i][lr] = acc0[i];
        part[w][16 + (q << 2) + i][lr] = acc1[i];
        part[w][32 + (q << 2) + i][lr] = acc2[i];
        part[w][48 + (q << 2) + i][lr] = acc3[i];
      }
      __syncthreads();
      // k-reduce quad + bias + tanh + mask + packed write-through store
      {
        f32x4 p0 = *(const f32x4*)&part[cch][qm][nq];
        f32x4 p1 = *(const f32x4*)&part[cch + 2][qm][nq];
        f32x4 p2 = *(const f32x4*)&part[cch + 4][qm][nq];
        f32x4 p3 = *(const f32x4*)&part[cch + 6][qm][nq];
        f32x4 sum = ((p0 + p1) + p2) + p3;
        float h0 = tanhf(sum[0] + qb[0]);
        float h1 = tanhf(sum[1] + qb[1]);
        float h2 = tanhf(sum[2] + qb[2]);
        float h3 = tanhf(sum[3] + qb[3]);
        size_t idx = ((size_t)l * BB + qm) * DD + qcol;
        u64 pk = (u64)f2b(h0) | ((u64)f2b(h1) << 16) |
                 ((u64)f2b(h2) << 32) | ((u64)f2b(h3) << 48);
        u64 val = (t < qlen) ? pk : *(const u64*)(Hp + idx);
        __hip_atomic_store((u64*)(Hc + idx), val, __ATOMIC_RELAXED,
                           __HIP_MEMORY_SCOPE_SYSTEM);
      }
      asm volatile("s_waitcnt vmcnt(0)" ::: "memory");  // stores at coherence pt
    }
    __syncthreads();  // all waves' stores drained

    const int ep = t + 1;
    // barrier arrival: one plain bypass store to our own flag line (no RMW)
    if (t < TT && tid == 0)
      __hip_atomic_store(&flags[bid << 5], ep, __ATOMIC_RELAXED,
                         __HIP_MEMORY_SCOPE_SYSTEM);

    // output projection for step t-1 (reads Hp; ring depth 4 makes this safe,
    // overlapped with other blocks' arrivals)
    if (t > 0) {
      const u16* h3p = Hp + (size_t)3 * BB * DD;
      const u16* hp = h3p + (size_t)opb * DD + (ln32 << 6);
      const u16* wp = WoT + (size_t)opv * DD + (ln32 << 6);
      float sacc = 0.f;
#pragma unroll
      for (int j = 0; j < 64; j += 8) {
        s16x8 hv8 = *(const s16x8*)(hp + j);
        s16x8 wv8 = *(const s16x8*)(wp + j);
#pragma unroll
        for (int e = 0; e < 8; ++e)
          sacc = fmaf(b2f((u16)hv8[e]), b2f((u16)wv8[e]), sacc);
      }
#pragma unroll
      for (int d = 16; d > 0; d >>= 1) sacc += __shfl_xor(sacc, d, 64);
      if (ln32 == 0)
        out[((size_t)opb * TT + (t - 1)) * VV + opv] = sacc + boutv;
    }

    // barrier wait: every block scans all 256 flags (parallel load round)
    if (t < TT) {
      for (;;) {
        int f = ep;
        if (lane < 32)
          f = __hip_atomic_load(&flags[fidx], __ATOMIC_RELAXED,
                                __HIP_MEMORY_SCOPE_SYSTEM);
        int ok = __all(f - ep >= 0);
        if (lane == 0) wok[w] = ok;
        __syncthreads();
        if (tid == 0)
          alldone = wok[0] & wok[1] & wok[2] & wok[3] &
                    wok[4] & wok[5] & wok[6] & wok[7];
        __syncthreads();
        if (alldone) break;
        __builtin_amdgcn_s_sleep(1);
      }
      // amortized acquire: invalidate L1/L2 once per 4 steps — exactly one
      // inv falls inside every buffer-reuse window (period 4), so no stale
      // cached state line can survive to its re-read.
      if ((ep & 3) == 0 && tid == 0)
        __hip_atomic_load(&flags[0], __ATOMIC_ACQUIRE, __HIP_MEMORY_SCOPE_AGENT);
      __syncthreads();
    }
  }
}

extern "C" void kernel_launch(void* const* d_in, const int* in_sizes, int n_in,
                              void* d_out, int out_size, void* d_ws, size_t ws_size,
                              hipStream_t stream) {
  const int* ids = (const int*)d_in[0];
  const int* slen = (const int*)d_in[1];
  const float* emb = (const float*)d_in[2];
  const float* Wx = (const float*)d_in[3];
  const float* bx = (const float*)d_in[4];
  const float* Wh = (const float*)d_in[5];
  const float* bh = (const float*)d_in[6];
  const float* Wout = (const float*)d_in[7];
  const float* bout = (const float*)d_in[8];
  float* out = (float*)d_out;

  char* ws = (char*)d_ws;
  const size_t oW = (size_t)LL * DD * DD * 2;   // 33,554,432 B per weight array
  const size_t oWoT = (size_t)VV * DD * 2;      // 262,144 B
  const size_t oEmb = (size_t)VV * DD * 2;      // 262,144 B
  const size_t oHb = (size_t)LL * BB * DD * 2;  // 1,048,576 B per ring buffer
  u16* Wxb = (u16*)ws;
  u16* Whb = (u16*)(ws + oW);
  u16* WoT = (u16*)(ws + 2 * oW);
  u16* embb = (u16*)(ws + 2 * oW + oWoT);
  u16* hb = (u16*)(ws + 2 * oW + oWoT + oEmb);      // ring of 4 state buffers
  int* flags = (int*)(ws + 2 * oW + oWoT + oEmb + 4 * oHb);

  // zero ring buffers + flag lines (graph replay re-runs this)
  hipMemsetAsync(ws + 2 * oW + oWoT + oEmb, 0, 4 * oHb + 32768, stream);

  const size_t n4 = (size_t)LL * DD * DD / 4;
  convert_w<<<dim3(4096), dim3(256), 0, stream>>>(Wx, Wxb, n4);
  convert_w<<<dim3(4096), dim3(256), 0, stream>>>(Wh, Whb, n4);
  convert_w<<<dim3(128), dim3(256), 0, stream>>>(emb, embb, (size_t)VV * DD / 4);
  convert_woT<<<dim3(512), dim3(256), 0, stream>>>(Wout, WoT);

  void* kp[12];
  kp[0] = (void*)&ids;  kp[1] = (void*)&slen;
  kp[2] = (void*)&bx;   kp[3] = (void*)&bh;   kp[4] = (void*)&embb;
  kp[5] = (void*)&Wxb;  kp[6] = (void*)&Whb;  kp[7] = (void*)&WoT;
  kp[8] = (void*)&bout; kp[9] = (void*)&hb;   kp[10] = (void*)&out;
  kp[11] = (void*)&flags;
  hipLaunchCooperativeKernel((const void*)persist, dim3(256), dim3(512), kp, 0, stream);
}

// Round 8
// 11683.202 us; speedup vs baseline: 1.5395x; 1.5092x over previous
//
#include <hip/hip_runtime.h>
#include <hip/hip_bf16.h>

#define TT 512
#define BB 64
#define DD 2048
#define LL 4
#define VV 64

typedef unsigned short u16;
typedef unsigned int u32;
typedef unsigned long long u64;
typedef __attribute__((ext_vector_type(8))) short s16x8;
typedef __attribute__((ext_vector_type(4))) float f32x4;

#define MFMA(a, b, c) __builtin_amdgcn_mfma_f32_16x16x32_bf16((a), (b), (c), 0, 0, 0)

#define GL(gp, lp)                                                        \
  __builtin_amdgcn_global_load_lds(                                       \
      (const __attribute__((address_space(1))) void*)(gp),                \
      (__attribute__((address_space(3))) void*)(lp), 16, 0, 0)

__device__ inline u16 f2b(float f) {
  u32 u = __builtin_bit_cast(u32, f);
  u32 r = (u + 0x7fffu + ((u >> 16) & 1u)) >> 16;
  return (u16)r;
}
__device__ inline float b2f(u16 b) {
  u32 u = ((u32)b) << 16;
  return __builtin_bit_cast(float, u);
}

__global__ __launch_bounds__(256) void convert_w(const float* __restrict__ src,
                                                 u16* __restrict__ dst, size_t n4) {
  size_t i = (size_t)blockIdx.x * 256 + threadIdx.x;
  size_t stride = (size_t)gridDim.x * 256;
  for (size_t j = i; j < n4; j += stride) {
    float4 f = ((const float4*)src)[j];
    ushort4 o;
    o.x = f2b(f.x); o.y = f2b(f.y); o.z = f2b(f.z); o.w = f2b(f.w);
    ((ushort4*)dst)[j] = o;
  }
}

// WoutT[v][k] = bf16(Wout[k][v]);  Wout is [2048][64] fp32
__global__ __launch_bounds__(256) void convert_woT(const float* __restrict__ Wout,
                                                   u16* __restrict__ WoT) {
  int g = blockIdx.x * 256 + threadIdx.x;  // 131072 total
  int v = g >> 11, k = g & 2047;
  WoT[(size_t)v * DD + k] = f2b(Wout[(size_t)k * VV + v]);
}

// idsT[t][b] = ids[b][t] : per-step id row becomes 4 contiguous cache lines
__global__ __launch_bounds__(256) void transpose_ids(const int* __restrict__ ids,
                                                     int* __restrict__ idsT) {
  int g = blockIdx.x * 256 + threadIdx.x;  // 32768
  int b = g >> 9, t = g & 511;
  idsT[t * BB + b] = ids[b * TT + t];
}

// Persistent kernel: 256 blocks x 512 threads, 1 block/CU.
// Block bid -> layer l = bid>>6, columns col0 = (bid&63)*32.
// Weights pinned in registers (32 x s16x8 = 128 regs/lane).
// A-operands staged block-cooperatively via global_load_lds into a 3-slot
// LDS ring (prefetch depth 2, counted vmcnt(4) + raw s_barrier per chunk)
// -> load depth no longer limited by the weight-filled register file.
// State stores write-through (SYSTEM bypass) to a 4-ring; one acquire-inv
// per 4 steps. Grid barrier: per-block flag store + all-block scan.
__global__ __launch_bounds__(512, 2)
void persist(const int* __restrict__ idsT, const int* __restrict__ slen,
             const float* __restrict__ bxp, const float* __restrict__ bhp,
             const u16* __restrict__ embb,
             const u16* __restrict__ Wxb, const u16* __restrict__ Whb,
             const u16* __restrict__ WoT, const float* __restrict__ bout,
             u16* hb, float* __restrict__ out, int* flags) {
  const int tid = threadIdx.x, bid = blockIdx.x;
  const int l = bid >> 6;
  const int col0 = (bid & 63) << 5;
  const int w = tid >> 6, lane = tid & 63;
  const int ks = w >> 1;               // compute k-slice (0..3)
  const int lr = lane & 15, q = lane >> 4;
  const int ncol = col0 + ((w & 1) << 4) + lr;
  const int kb0 = (ks << 9) + (q << 3);
  const size_t HSZ = (size_t)LL * BB * DD;

  // ---- load weight fragments (once), pin as opaque ----
  s16x8 wx[16], wh[16];
  {
    const u16* p0 = Wxb + ((size_t)l * DD + ncol) * DD + kb0;
    const u16* p1 = Whb + ((size_t)l * DD + ncol) * DD + kb0;
#pragma unroll
    for (int kt = 0; kt < 16; ++kt) {
      wx[kt] = *(const s16x8*)(p0 + (kt << 5));
      wh[kt] = *(const s16x8*)(p1 + (kt << 5));
    }
  }
#pragma unroll
  for (int kt = 0; kt < 16; ++kt) {
    asm("" : "+v"(wx[kt]));
    asm("" : "+v"(wh[kt]));
  }

  // ---- out-proj assignment: 4 batch rows x 4 vocab cols per block ----
  const int opo = tid >> 5, ln32 = tid & 31;
  const int opb = ((bid >> 4) << 2) + (opo >> 2);
  const int opv = ((bid & 15) << 2) + (opo & 3);
  const float boutv = bout[opv];

  // ---- reduce-quad mapping ----
  const int cch = tid >> 8;
  const int qm = (tid >> 2) & 63;
  const int nq = (tid & 3) << 2;
  const int qcol = col0 + (cch << 4) + nq;
  float qb[4];
#pragma unroll
  for (int e = 0; e < 4; ++e)
    qb[e] = bxp[l * DD + qcol + e] + bhp[l * DD + qcol + e];
  const int qlen = slen[qm];

  // staging lane mapping (bijection; makes each 16-lane read group contiguous)
  const int sS = lane >> 4;                       // k-slot 0..3 (8 elems each)
  const int sR = (lane & 15) ^ ((sS << 1) & 15);  // source row within group
  // compute-side ds_read offset (u16 units) within a 512-elem region
  const int elemOff = ((q << 4) | (lr ^ ((q << 1) & 15))) << 3;

  // barrier scan assignment
  const int fidx = ((w << 5) + (lane & 31)) << 5;

  __shared__ u16 stg[3][16384];                 // 3 x 32KB staging slots
  __shared__ __align__(16) float part[8][64][20];
  __shared__ int sids[64];
  __shared__ int wok[8];
  __shared__ int alldone;

  for (int t = 0; t <= TT; ++t) {
    const u16* Hp = hb + (size_t)((t + 3) & 3) * HSZ;
    u16* Hc = hb + (size_t)(t & 3) * HSZ;

    if (t < TT) {
      if (tid < BB) sids[tid] = idsT[t * BB + tid];
      __syncthreads();   // full drain: vmcnt=0 before staging issues

      // per-wave staging source rows: src = w>>2 (0=x,1=h), ks_e = w&3
      const int kofs0 = ((w & 3) << 9) + (sS << 3);
      const u16 *sr0, *sr1, *sr2, *sr3;
      if (w < 4) {
        if (l == 0) {
          sr0 = embb + (size_t)sids[sR] * DD + kofs0;
          sr1 = embb + (size_t)sids[16 + sR] * DD + kofs0;
          sr2 = embb + (size_t)sids[32 + sR] * DD + kofs0;
          sr3 = embb + (size_t)sids[48 + sR] * DD + kofs0;
        } else {
          const u16* xsrc = Hp + (size_t)(l - 1) * BB * DD;
          sr0 = xsrc + (size_t)sR * DD + kofs0;
          sr1 = xsrc + (size_t)(16 + sR) * DD + kofs0;
          sr2 = xsrc + (size_t)(32 + sR) * DD + kofs0;
          sr3 = xsrc + (size_t)(48 + sR) * DD + kofs0;
        }
      } else {
        const u16* hsrc = Hp + (size_t)l * BB * DD;
        sr0 = hsrc + (size_t)sR * DD + kofs0;
        sr1 = hsrc + (size_t)(16 + sR) * DD + kofs0;
        sr2 = hsrc + (size_t)(32 + sR) * DD + kofs0;
        sr3 = hsrc + (size_t)(48 + sR) * DD + kofs0;
      }
      const int eb = (w << 2) << 9;  // this wave's 4 dest regions (x512 u16)

      // prologue: issue chunks 0,1
#pragma unroll
      for (int c = 0; c < 2; ++c) {
        GL(sr0 + (c << 5), &stg[c][eb]);
        GL(sr1 + (c << 5), &stg[c][eb + (1 << 9)]);
        GL(sr2 + (c << 5), &stg[c][eb + (2 << 9)]);
        GL(sr3 + (c << 5), &stg[c][eb + (3 << 9)]);
      }

      f32x4 acc0 = {0, 0, 0, 0}, acc1 = {0, 0, 0, 0};
      f32x4 acc2 = {0, 0, 0, 0}, acc3 = {0, 0, 0, 0};
      const int xb = ((ks << 2) << 9) + elemOff;
      const int hbofs = ((16 + (ks << 2)) << 9) + elemOff;

#pragma unroll
      for (int j = 0; j < 16; ++j) {
        if (j < 15) asm volatile("s_waitcnt vmcnt(4)" ::: "memory");
        else        asm volatile("s_waitcnt vmcnt(0)" ::: "memory");
        asm volatile("s_barrier" ::: "memory");
        if (j + 2 < 16) {
          const int sl = (j + 2) % 3, co = (j + 2) << 5;
          GL(sr0 + co, &stg[sl][eb]);
          GL(sr1 + co, &stg[sl][eb + (1 << 9)]);
          GL(sr2 + co, &stg[sl][eb + (2 << 9)]);
          GL(sr3 + co, &stg[sl][eb + (3 << 9)]);
        }
        const u16* sb = stg[j % 3];
        s16x8 ax0 = *(const s16x8*)&sb[xb];
        s16x8 ax1 = *(const s16x8*)&sb[xb + (1 << 9)];
        s16x8 ax2 = *(const s16x8*)&sb[xb + (2 << 9)];
        s16x8 ax3 = *(const s16x8*)&sb[xb + (3 << 9)];
        s16x8 ah0 = *(const s16x8*)&sb[hbofs];
        s16x8 ah1 = *(const s16x8*)&sb[hbofs + (1 << 9)];
        s16x8 ah2 = *(const s16x8*)&sb[hbofs + (2 << 9)];
        s16x8 ah3 = *(const s16x8*)&sb[hbofs + (3 << 9)];
        acc0 = MFMA(ax0, wx[j], acc0); acc0 = MFMA(ah0, wh[j], acc0);
        acc1 = MFMA(ax1, wx[j], acc1); acc1 = MFMA(ah1, wh[j], acc1);
        acc2 = MFMA(ax2, wx[j], acc2); acc2 = MFMA(ah2, wh[j], acc2);
        acc3 = MFMA(ax3, wx[j], acc3); acc3 = MFMA(ah3, wh[j], acc3);
      }

#pragma unroll
      for (int i = 0; i < 4; ++i) {
        part[w][(q << 2) + i][lr] = acc0[i];
        part[w][16 + (q << 2) + i][lr] = acc1[i];
        part[w][32 + (q << 2) + i][lr] = acc2[i];
        part[w][48 + (q << 2) + i][lr] = acc3[i];
      }
      __syncthreads();
      // k-reduce quad + bias + tanh + mask + packed write-through store
      {
        f32x4 p0 = *(const f32x4*)&part[cch][qm][nq];
        f32x4 p1 = *(const f32x4*)&part[cch + 2][qm][nq];
        f32x4 p2 = *(const f32x4*)&part[cch + 4][qm][nq];
        f32x4 p3 = *(const f32x4*)&part[cch + 6][qm][nq];
        f32x4 sum = ((p0 + p1) + p2) + p3;
        float h0 = tanhf(sum[0] + qb[0]);
        float h1 = tanhf(sum[1] + qb[1]);
        float h2 = tanhf(sum[2] + qb[2]);
        float h3 = tanhf(sum[3] + qb[3]);
        size_t idx = ((size_t)l * BB + qm) * DD + qcol;
        u64 pk = (u64)f2b(h0) | ((u64)f2b(h1) << 16) |
                 ((u64)f2b(h2) << 32) | ((u64)f2b(h3) << 48);
        u64 val = (t < qlen) ? pk : *(const u64*)(Hp + idx);
        __hip_atomic_store((u64*)(Hc + idx), val, __ATOMIC_RELAXED,
                           __HIP_MEMORY_SCOPE_SYSTEM);
      }
      asm volatile("s_waitcnt vmcnt(0)" ::: "memory");
    }
    __syncthreads();

    const int ep = t + 1;
    if (t < TT && tid == 0)
      __hip_atomic_store(&flags[bid << 5], ep, __ATOMIC_RELAXED,
                         __HIP_MEMORY_SCOPE_SYSTEM);

    // output projection for step t-1 (reads Hp; ring depth 4 makes it safe)
    if (t > 0) {
      const u16* h3p = Hp + (size_t)3 * BB * DD;
      const u16* hp = h3p + (size_t)opb * DD + (ln32 << 6);
      const u16* wp = WoT + (size_t)opv * DD + (ln32 << 6);
      float sacc = 0.f;
#pragma unroll
      for (int j = 0; j < 64; j += 8) {
        s16x8 hv8 = *(const s16x8*)(hp + j);
        s16x8 wv8 = *(const s16x8*)(wp + j);
#pragma unroll
        for (int e = 0; e < 8; ++e)
          sacc = fmaf(b2f((u16)hv8[e]), b2f((u16)wv8[e]), sacc);
      }
#pragma unroll
      for (int d = 16; d > 0; d >>= 1) sacc += __shfl_xor(sacc, d, 64);
      if (ln32 == 0)
        out[((size_t)opb * TT + (t - 1)) * VV + opv] = sacc + boutv;
    }

    if (t < TT) {
      for (;;) {
        int f = ep;
        if (lane < 32)
          f = __hip_atomic_load(&flags[fidx], __ATOMIC_RELAXED,
                                __HIP_MEMORY_SCOPE_SYSTEM);
        int ok = __all(f - ep >= 0);
        if (lane == 0) wok[w] = ok;
        __syncthreads();
        if (tid == 0)
          alldone = wok[0] & wok[1] & wok[2] & wok[3] &
                    wok[4] & wok[5] & wok[6] & wok[7];
        __syncthreads();
        if (alldone) break;
        __builtin_amdgcn_s_sleep(1);
      }
      // amortized acquire: one L1/L2 inv per 4 steps covers the 4-deep ring
      if ((ep & 3) == 0 && tid == 0)
        __hip_atomic_load(&flags[0], __ATOMIC_ACQUIRE, __HIP_MEMORY_SCOPE_AGENT);
      __syncthreads();
    }
  }
}

extern "C" void kernel_launch(void* const* d_in, const int* in_sizes, int n_in,
                              void* d_out, int out_size, void* d_ws, size_t ws_size,
                              hipStream_t stream) {
  const int* ids = (const int*)d_in[0];
  const int* slen = (const int*)d_in[1];
  const float* emb = (const float*)d_in[2];
  const float* Wx = (const float*)d_in[3];
  const float* bx = (const float*)d_in[4];
  const float* Wh = (const float*)d_in[5];
  const float* bh = (const float*)d_in[6];
  const float* Wout = (const float*)d_in[7];
  const float* bout = (const float*)d_in[8];
  float* out = (float*)d_out;

  char* ws = (char*)d_ws;
  const size_t oW = (size_t)LL * DD * DD * 2;
  const size_t oWoT = (size_t)VV * DD * 2;
  const size_t oEmb = (size_t)VV * DD * 2;
  const size_t oHb = (size_t)LL * BB * DD * 2;
  u16* Wxb = (u16*)ws;
  u16* Whb = (u16*)(ws + oW);
  u16* WoT = (u16*)(ws + 2 * oW);
  u16* embb = (u16*)(ws + 2 * oW + oWoT);
  u16* hb = (u16*)(ws + 2 * oW + oWoT + oEmb);          // 4-ring state
  int* flags = (int*)(ws + 2 * oW + oWoT + oEmb + 4 * oHb);
  int* idsT = (int*)(ws + 2 * oW + oWoT + oEmb + 4 * oHb + 32768);

  hipMemsetAsync(ws + 2 * oW + oWoT + oEmb, 0, 4 * oHb + 32768, stream);

  const size_t n4 = (size_t)LL * DD * DD / 4;
  convert_w<<<dim3(4096), dim3(256), 0, stream>>>(Wx, Wxb, n4);
  convert_w<<<dim3(4096), dim3(256), 0, stream>>>(Wh, Whb, n4);
  convert_w<<<dim3(128), dim3(256), 0, stream>>>(emb, embb, (size_t)VV * DD / 4);
  convert_woT<<<dim3(512), dim3(256), 0, stream>>>(Wout, WoT);
  transpose_ids<<<dim3(128), dim3(256), 0, stream>>>(ids, idsT);

  void* kp[12];
  kp[0] = (void*)&idsT; kp[1] = (void*)&slen;
  kp[2] = (void*)&bx;   kp[3] = (void*)&bh;   kp[4] = (void*)&embb;
  kp[5] = (void*)&Wxb;  kp[6] = (void*)&Whb;  kp[7] = (void*)&WoT;
  kp[8] = (void*)&bout; kp[9] = (void*)&hb;   kp[10] = (void*)&out;
  kp[11] = (void*)&flags;
  hipLaunchCooperativeKernel((const void*)persist, dim3(256), dim3(512), kp, 0, stream);
}

// Round 10
// 7678.610 us; speedup vs baseline: 2.3423x; 1.5215x over previous
//
#include <hip/hip_runtime.h>
#include <hip/hip_bf16.h>

#define TT 512
#define BB 64
#define DD 2048
#define LL 4
#define VV 64

typedef unsigned short u16;
typedef unsigned int u32;
typedef unsigned long long u64;
typedef __attribute__((ext_vector_type(8))) short s16x8;
typedef __attribute__((ext_vector_type(4))) float f32x4;

#define MFMA(a, b, c) __builtin_amdgcn_mfma_f32_16x16x32_bf16((a), (b), (c), 0, 0, 0)

#define GL(gp, lp)                                                        \
  __builtin_amdgcn_global_load_lds(                                       \
      (const __attribute__((address_space(1))) void*)(gp),                \
      (__attribute__((address_space(3))) void*)(lp), 16, 0, 0)

__device__ inline u16 f2b(float f) {
  u32 u = __builtin_bit_cast(u32, f);
  u32 r = (u + 0x7fffu + ((u >> 16) & 1u)) >> 16;
  return (u16)r;
}
__device__ inline float b2f(u16 b) {
  u32 u = ((u32)b) << 16;
  return __builtin_bit_cast(float, u);
}

__global__ __launch_bounds__(256) void convert_w(const float* __restrict__ src,
                                                 u16* __restrict__ dst, size_t n4) {
  size_t i = (size_t)blockIdx.x * 256 + threadIdx.x;
  size_t stride = (size_t)gridDim.x * 256;
  for (size_t j = i; j < n4; j += stride) {
    float4 f = ((const float4*)src)[j];
    ushort4 o;
    o.x = f2b(f.x); o.y = f2b(f.y); o.z = f2b(f.z); o.w = f2b(f.w);
    ((ushort4*)dst)[j] = o;
  }
}

__global__ __launch_bounds__(256) void convert_woT(const float* __restrict__ Wout,
                                                   u16* __restrict__ WoT) {
  int g = blockIdx.x * 256 + threadIdx.x;
  int v = g >> 11, k = g & 2047;
  WoT[(size_t)v * DD + k] = f2b(Wout[(size_t)k * VV + v]);
}

__global__ __launch_bounds__(256) void transpose_ids(const int* __restrict__ ids,
                                                     int* __restrict__ idsT) {
  int g = blockIdx.x * 256 + threadIdx.x;
  int b = g >> 9, t = g & 511;
  idsT[t * BB + b] = ids[b * TT + t];
}

// Persistent: 256 blocks x 512 threads, 1 block/CU. Block -> (layer, 32 cols).
// Decomposition: 8 waves split K (256 each), each wave computes ALL 32
// block-cols for its K-slice and stages ITS OWN x/h chunks into wave-private
// LDS double-buffer -> no intra-step barriers; waves self-pace on counted
// vmcnt. Cross-wave K-combine: one 8-way LDS reduce (part unioned w/ stg).
// Weights pinned in regs (2 ctiles x 8 chunks x2 = 128 regs). State: 4-ring,
// SYSTEM-bypass stores, acquire-inv every 4 steps, flag-scan grid barrier.
__global__ __launch_bounds__(512, 2)
void persist(const int* __restrict__ idsT, const int* __restrict__ slen,
             const float* __restrict__ bxp, const float* __restrict__ bhp,
             const u16* __restrict__ embb,
             const u16* __restrict__ Wxb, const u16* __restrict__ Whb,
             const u16* __restrict__ WoT, const float* __restrict__ bout,
             u16* hb, float* __restrict__ out, int* flags) {
  const int tid = threadIdx.x, bid = blockIdx.x;
  const int l = bid >> 6;
  const int col0 = (bid & 63) << 5;
  const int w = tid >> 6, lane = tid & 63;
  const int lr = lane & 15, q = lane >> 4;
  const size_t HSZ = (size_t)LL * BB * DD;

  // ---- weight frags: [ctile][chunk], k = w*256 + j*32 + q*8 ----
  s16x8 wx[2][8], wh[2][8];
#pragma unroll
  for (int c = 0; c < 2; ++c) {
    const int ncol = col0 + (c << 4) + lr;
    const u16* p0 = Wxb + ((size_t)l * DD + ncol) * DD + (w << 8) + (q << 3);
    const u16* p1 = Whb + ((size_t)l * DD + ncol) * DD + (w << 8) + (q << 3);
#pragma unroll
    for (int j = 0; j < 8; ++j) {
      wx[c][j] = *(const s16x8*)(p0 + (j << 5));
      wh[c][j] = *(const s16x8*)(p1 + (j << 5));
    }
  }
#pragma unroll
  for (int c = 0; c < 2; ++c)
#pragma unroll
    for (int j = 0; j < 8; ++j) {
      asm("" : "+v"(wx[c][j]));
      asm("" : "+v"(wh[c][j]));
    }

  // ---- out-proj: 4 batch x 4 vocab per block ----
  const int opo = tid >> 5, ln32 = tid & 31;
  const int opb = ((bid >> 4) << 2) + (opo >> 2);
  const int opv = ((bid & 15) << 2) + (opo & 3);
  const float boutv = bout[opv];

  // ---- reduce mapping: thread -> (row, col-quad) ----
  const int rm = tid >> 3;
  const int rng = (tid & 7) << 2;
  const int qcol = col0 + rng;
  float qb[4];
#pragma unroll
  for (int e = 0; e < 4; ++e)
    qb[e] = bxp[l * DD + qcol + e] + bhp[l * DD + qcol + e];
  const int qlen = slen[rm];

  // ---- staging lane decomposition (source pre-permuted; rule #21) ----
  const int lrow = lane >> 2;                              // row within 16-group
  const int lelem = ((lane & 3) ^ ((lane >> 3) & 3)) << 3; // swizzled elem off
  // ds_read side swizzle: piece = q ^ ((lr>>1)&3)
  const int fx = lr * 32 + ((q ^ ((lr >> 1) & 3)) << 3);   // within-slot frag base

  const int fidx = ((w << 5) + (lane & 31)) << 5;          // barrier scan flag

  // LDS: stg (8 waves x 2 slots x 8KB = 128KB) UNION part[8][64][36] (72KB)
  __shared__ __align__(16) u16 stg[65536];
  float* part = (float*)stg;
  __shared__ int sids[64];
  __shared__ int wok[8];
  __shared__ int alldone;

  u16* wslot = stg + (w << 13);  // wave-private 16KB

  for (int t = 0; t <= TT; ++t) {
    const u16* Hp = hb + (size_t)((t + 3) & 3) * HSZ;
    u16* Hc = hb + (size_t)(t & 3) * HSZ;

    if (t < TT) {
      if (l == 0) {
        if (tid < BB) sids[tid] = idsT[t * BB + tid];
        __syncthreads();
      }
      // per-lane staging source pointers (4 row-groups x {x,h})
      const int kw = (w << 8) + lelem;
      const u16* hb0 = Hp + (size_t)l * BB * DD + kw;
      const u16 *px0, *px1, *px2, *px3;
      if (l == 0) {
        px0 = embb + (size_t)sids[lrow] * DD + kw;
        px1 = embb + (size_t)sids[16 + lrow] * DD + kw;
        px2 = embb + (size_t)sids[32 + lrow] * DD + kw;
        px3 = embb + (size_t)sids[48 + lrow] * DD + kw;
      } else {
        const u16* xb0 = Hp + (size_t)(l - 1) * BB * DD + kw;
        px0 = xb0 + (size_t)lrow * DD;
        px1 = xb0 + (size_t)(16 + lrow) * DD;
        px2 = xb0 + (size_t)(32 + lrow) * DD;
        px3 = xb0 + (size_t)(48 + lrow) * DD;
      }
      const u16* ph0 = hb0 + (size_t)lrow * DD;
      const u16* ph1 = hb0 + (size_t)(16 + lrow) * DD;
      const u16* ph2 = hb0 + (size_t)(32 + lrow) * DD;
      const u16* ph3 = hb0 + (size_t)(48 + lrow) * DD;

      // prologue: stage chunks 0,1 (8 GLs each)
#pragma unroll
      for (int c = 0; c < 2; ++c) {
        u16* d = wslot + (c << 12);
        GL(px0 + (c << 5), d);
        GL(px1 + (c << 5), d + 512);
        GL(px2 + (c << 5), d + 1024);
        GL(px3 + (c << 5), d + 1536);
        GL(ph0 + (c << 5), d + 2048);
        GL(ph1 + (c << 5), d + 2560);
        GL(ph2 + (c << 5), d + 3072);
        GL(ph3 + (c << 5), d + 3584);
      }

      f32x4 acc[2][4] = {{{0,0,0,0},{0,0,0,0},{0,0,0,0},{0,0,0,0}},
                         {{0,0,0,0},{0,0,0,0},{0,0,0,0},{0,0,0,0}}};
#pragma unroll
      for (int j = 0; j < 8; ++j) {
        if (j < 7) asm volatile("s_waitcnt vmcnt(8)" ::: "memory");
        else       asm volatile("s_waitcnt vmcnt(0)" ::: "memory");
        __builtin_amdgcn_sched_barrier(0);
        const u16* sb = wslot + ((j & 1) << 12);
        s16x8 ax0 = *(const s16x8*)(sb + fx);
        s16x8 ax1 = *(const s16x8*)(sb + 512 + fx);
        s16x8 ax2 = *(const s16x8*)(sb + 1024 + fx);
        s16x8 ax3 = *(const s16x8*)(sb + 1536 + fx);
        s16x8 ah0 = *(const s16x8*)(sb + 2048 + fx);
        s16x8 ah1 = *(const s16x8*)(sb + 2560 + fx);
        s16x8 ah2 = *(const s16x8*)(sb + 3072 + fx);
        s16x8 ah3 = *(const s16x8*)(sb + 3584 + fx);
        asm volatile("s_waitcnt lgkmcnt(0)" ::: "memory");
        __builtin_amdgcn_sched_barrier(0);
        if (j < 6) {  // refill same slot with chunk j+2 (reads done)
          u16* d = wslot + ((j & 1) << 12);
          const int co = (j + 2) << 5;
          GL(px0 + co, d);
          GL(px1 + co, d + 512);
          GL(px2 + co, d + 1024);
          GL(px3 + co, d + 1536);
          GL(ph0 + co, d + 2048);
          GL(ph1 + co, d + 2560);
          GL(ph2 + co, d + 3072);
          GL(ph3 + co, d + 3584);
        }
#pragma unroll
        for (int c = 0; c < 2; ++c) {
          acc[c][0] = MFMA(ax0, wx[c][j], acc[c][0]);
          acc[c][0] = MFMA(ah0, wh[c][j], acc[c][0]);
          acc[c][1] = MFMA(ax1, wx[c][j], acc[c][1]);
          acc[c][1] = MFMA(ah1, wh[c][j], acc[c][1]);
          acc[c][2] = MFMA(ax2, wx[c][j], acc[c][2]);
          acc[c][2] = MFMA(ah2, wh[c][j], acc[c][2]);
          acc[c][3] = MFMA(ax3, wx[c][j], acc[c][3]);
          acc[c][3] = MFMA(ah3, wh[c][j], acc[c][3]);
        }
      }

      __syncthreads();  // all waves done reading stg; part may overwrite
#pragma unroll
      for (int c = 0; c < 2; ++c)
#pragma unroll
        for (int mt = 0; mt < 4; ++mt)
#pragma unroll
          for (int i = 0; i < 4; ++i)
            part[((w << 6) + (mt << 4) + (q << 2) + i) * 36 + (c << 4) + lr] =
                acc[c][mt][i];
      __syncthreads();

      // 8-way K-combine + bias + tanh + mask + packed bypass store
      {
        f32x4 sum = {0, 0, 0, 0};
#pragma unroll
        for (int k2 = 0; k2 < 8; ++k2)
          sum += *(const f32x4*)&part[((k2 << 6) + rm) * 36 + rng];
        float h0 = tanhf(sum[0] + qb[0]);
        float h1 = tanhf(sum[1] + qb[1]);
        float h2 = tanhf(sum[2] + qb[2]);
        float h3 = tanhf(sum[3] + qb[3]);
        size_t idx = ((size_t)l * BB + rm) * DD + qcol;
        u64 pk = (u64)f2b(h0) | ((u64)f2b(h1) << 16) |
                 ((u64)f2b(h2) << 32) | ((u64)f2b(h3) << 48);
        u64 val = (t < qlen) ? pk : *(const u64*)(Hp + idx);
        __hip_atomic_store((u64*)(Hc + idx), val, __ATOMIC_RELAXED,
                           __HIP_MEMORY_SCOPE_SYSTEM);
      }
      asm volatile("s_waitcnt vmcnt(0)" ::: "memory");
    }
    __syncthreads();

    const int ep = t + 1;
    if (t < TT && tid == 0)
      __hip_atomic_store(&flags[bid << 5], ep, __ATOMIC_RELAXED,
                         __HIP_MEMORY_SCOPE_SYSTEM);

    // out-proj for step t-1 (Hp), overlapped with other blocks' arrivals
    if (t > 0) {
      const u16* h3p = Hp + (size_t)3 * BB * DD;
      const u16* hp = h3p + (size_t)opb * DD + (ln32 << 6);
      const u16* wp = WoT + (size_t)opv * DD + (ln32 << 6);
      float sacc = 0.f;
#pragma unroll
      for (int j = 0; j < 64; j += 8) {
        s16x8 hv8 = *(const s16x8*)(hp + j);
        s16x8 wv8 = *(const s16x8*)(wp + j);
#pragma unroll
        for (int e = 0; e < 8; ++e)
          sacc = fmaf(b2f((u16)hv8[e]), b2f((u16)wv8[e]), sacc);
      }
#pragma unroll
      for (int d = 16; d > 0; d >>= 1) sacc += __shfl_xor(sacc, d, 64);
      if (ln32 == 0)
        out[((size_t)opb * TT + (t - 1)) * VV + opv] = sacc + boutv;
    }

    if (t < TT) {
      for (;;) {
        int f = ep;
        if (lane < 32)
          f = __hip_atomic_load(&flags[fidx], __ATOMIC_RELAXED,
                                __HIP_MEMORY_SCOPE_SYSTEM);
        int ok = __all(f - ep >= 0);
        if (lane == 0) wok[w] = ok;
        __syncthreads();
        if (tid == 0)
          alldone = wok[0] & wok[1] & wok[2] & wok[3] &
                    wok[4] & wok[5] & wok[6] & wok[7];
        __syncthreads();
        if (alldone) break;
        __builtin_amdgcn_s_sleep(1);
      }
      if ((ep & 3) == 0 && tid == 0)
        __hip_atomic_load(&flags[0], __ATOMIC_ACQUIRE, __HIP_MEMORY_SCOPE_AGENT);
      __syncthreads();
    }
  }
}

extern "C" void kernel_launch(void* const* d_in, const int* in_sizes, int n_in,
                              void* d_out, int out_size, void* d_ws, size_t ws_size,
                              hipStream_t stream) {
  const int* ids = (const int*)d_in[0];
  const int* slen = (const int*)d_in[1];
  const float* emb = (const float*)d_in[2];
  const float* Wx = (const float*)d_in[3];
  const float* bx = (const float*)d_in[4];
  const float* Wh = (const float*)d_in[5];
  const float* bh = (const float*)d_in[6];
  const float* Wout = (const float*)d_in[7];
  const float* bout = (const float*)d_in[8];
  float* out = (float*)d_out;

  char* ws = (char*)d_ws;
  const size_t oW = (size_t)LL * DD * DD * 2;
  const size_t oWoT = (size_t)VV * DD * 2;
  const size_t oEmb = (size_t)VV * DD * 2;
  const size_t oHb = (size_t)LL * BB * DD * 2;
  u16* Wxb = (u16*)ws;
  u16* Whb = (u16*)(ws + oW);
  u16* WoT = (u16*)(ws + 2 * oW);
  u16* embb = (u16*)(ws + 2 * oW + oWoT);
  u16* hb = (u16*)(ws + 2 * oW + oWoT + oEmb);          // 4-ring state
  int* flags = (int*)(ws + 2 * oW + oWoT + oEmb + 4 * oHb);
  int* idsT = (int*)(ws + 2 * oW + oWoT + oEmb + 4 * oHb + 32768);

  hipMemsetAsync(ws + 2 * oW + oWoT + oEmb, 0, 4 * oHb + 32768, stream);

  const size_t n4 = (size_t)LL * DD * DD / 4;
  convert_w<<<dim3(4096), dim3(256), 0, stream>>>(Wx, Wxb, n4);
  convert_w<<<dim3(4096), dim3(256), 0, stream>>>(Wh, Whb, n4);
  convert_w<<<dim3(128), dim3(256), 0, stream>>>(emb, embb, (size_t)VV * DD / 4);
  convert_woT<<<dim3(512), dim3(256), 0, stream>>>(Wout, WoT);
  transpose_ids<<<dim3(128), dim3(256), 0, stream>>>(ids, idsT);

  void* kp[12];
  kp[0] = (void*)&idsT; kp[1] = (void*)&slen;
  kp[2] = (void*)&bx;   kp[3] = (void*)&bh;   kp[4] = (void*)&embb;
  kp[5] = (void*)&Wxb;  kp[6] = (void*)&Whb;  kp[7] = (void*)&WoT;
  kp[8] = (void*)&bout; kp[9] = (void*)&hb;   kp[10] = (void*)&out;
  kp[11] = (void*)&flags;
  hipLaunchCooperativeKernel((const void*)persist, dim3(256), dim3(512), kp, 0, stream);
}

// Round 12
// 7628.575 us; speedup vs baseline: 2.3577x; 1.0066x over previous
//
#include <hip/hip_runtime.h>
#include <hip/hip_bf16.h>

#define TT 512
#define BB 64
#define DD 2048
#define LL 4
#define VV 64

typedef unsigned short u16;
typedef unsigned int u32;
typedef unsigned long long u64;
typedef __attribute__((ext_vector_type(8))) short s16x8;
typedef __attribute__((ext_vector_type(4))) float f32x4;

#define MFMA(a, b, c) __builtin_amdgcn_mfma_f32_16x16x32_bf16((a), (b), (c), 0, 0, 0)

#define GL(gp, lp)                                                        \
  __builtin_amdgcn_global_load_lds(                                       \
      (const __attribute__((address_space(1))) void*)(gp),                \
      (__attribute__((address_space(3))) void*)(lp), 16, 0, 0)

__device__ inline u16 f2b(float f) {
  u32 u = __builtin_bit_cast(u32, f);
  u32 r = (u + 0x7fffu + ((u >> 16) & 1u)) >> 16;
  return (u16)r;
}
__device__ inline float b2f(u16 b) {
  u32 u = ((u32)b) << 16;
  return __builtin_bit_cast(float, u);
}

__global__ __launch_bounds__(256) void convert_w(const float* __restrict__ src,
                                                 u16* __restrict__ dst, size_t n4) {
  size_t i = (size_t)blockIdx.x * 256 + threadIdx.x;
  size_t stride = (size_t)gridDim.x * 256;
  for (size_t j = i; j < n4; j += stride) {
    float4 f = ((const float4*)src)[j];
    ushort4 o;
    o.x = f2b(f.x); o.y = f2b(f.y); o.z = f2b(f.z); o.w = f2b(f.w);
    ((ushort4*)dst)[j] = o;
  }
}

__global__ __launch_bounds__(256) void convert_woT(const float* __restrict__ Wout,
                                                   u16* __restrict__ WoT) {
  int g = blockIdx.x * 256 + threadIdx.x;
  int v = g >> 11, k = g & 2047;
  WoT[(size_t)v * DD + k] = f2b(Wout[(size_t)k * VV + v]);
}

__global__ __launch_bounds__(256) void transpose_ids(const int* __restrict__ ids,
                                                     int* __restrict__ idsT) {
  int g = blockIdx.x * 256 + threadIdx.x;
  int b = g >> 9, t = g & 511;
  idsT[t * BB + b] = ids[b * TT + t];
}

// Persistent: 256 blocks x 512 threads, 1 block/CU. Block -> (layer, 32 cols).
// 8 waves split K (256 each); wave-private LDS double-buffer staging via
// global_load_lds, self-paced on counted vmcnt (no intra-step barriers).
// Cross-wave K-combine: one 8-way LDS reduce. Weights pinned in regs.
// State: 4-ring, AGENT-scope (sc1) write-through stores -> land in die-level
// L3 (agent coherence point, cross-XCD visible) instead of DRAM; acquire-inv
// every 4 steps bounds staleness exactly as before. Flags: AGENT store +
// AGENT scan loads (L3 polls, not DRAM).
__global__ __launch_bounds__(512, 2)
void persist(const int* __restrict__ idsT, const int* __restrict__ slen,
             const float* __restrict__ bxp, const float* __restrict__ bhp,
             const u16* __restrict__ embb,
             const u16* __restrict__ Wxb, const u16* __restrict__ Whb,
             const u16* __restrict__ WoT, const float* __restrict__ bout,
             u16* hb, float* __restrict__ out, int* flags) {
  const int tid = threadIdx.x, bid = blockIdx.x;
  const int l = bid >> 6;
  const int col0 = (bid & 63) << 5;
  const int w = tid >> 6, lane = tid & 63;
  const int lr = lane & 15, q = lane >> 4;
  const size_t HSZ = (size_t)LL * BB * DD;

  // ---- weight frags: [ctile][chunk], k = w*256 + j*32 + q*8 ----
  s16x8 wx[2][8], wh[2][8];
#pragma unroll
  for (int c = 0; c < 2; ++c) {
    const int ncol = col0 + (c << 4) + lr;
    const u16* p0 = Wxb + ((size_t)l * DD + ncol) * DD + (w << 8) + (q << 3);
    const u16* p1 = Whb + ((size_t)l * DD + ncol) * DD + (w << 8) + (q << 3);
#pragma unroll
    for (int j = 0; j < 8; ++j) {
      wx[c][j] = *(const s16x8*)(p0 + (j << 5));
      wh[c][j] = *(const s16x8*)(p1 + (j << 5));
    }
  }
#pragma unroll
  for (int c = 0; c < 2; ++c)
#pragma unroll
    for (int j = 0; j < 8; ++j) {
      asm("" : "+v"(wx[c][j]));
      asm("" : "+v"(wh[c][j]));
    }

  // ---- out-proj: 4 batch x 4 vocab per block ----
  const int opo = tid >> 5, ln32 = tid & 31;
  const int opb = ((bid >> 4) << 2) + (opo >> 2);
  const int opv = ((bid & 15) << 2) + (opo & 3);
  const float boutv = bout[opv];

  // ---- reduce mapping: thread -> (row, col-quad) ----
  const int rm = tid >> 3;
  const int rng = (tid & 7) << 2;
  const int qcol = col0 + rng;
  float qb[4];
#pragma unroll
  for (int e = 0; e < 4; ++e)
    qb[e] = bxp[l * DD + qcol + e] + bhp[l * DD + qcol + e];
  const int qlen = slen[rm];

  // ---- staging lane decomposition (source pre-permuted; rule #21) ----
  const int lrow = lane >> 2;                              // row within 16-group
  const int lelem = ((lane & 3) ^ ((lane >> 3) & 3)) << 3; // swizzled elem off
  // ds_read side swizzle: piece = q ^ ((lr>>1)&3)
  const int fx = lr * 32 + ((q ^ ((lr >> 1) & 3)) << 3);   // within-slot frag base

  const int fidx = ((w << 5) + (lane & 31)) << 5;          // barrier scan flag

  // LDS: stg (8 waves x 2 slots x 8KB = 128KB) UNION part[8][64][36] (72KB)
  __shared__ __align__(16) u16 stg[65536];
  float* part = (float*)stg;
  __shared__ int sids[64];
  __shared__ int wok[8];
  __shared__ int alldone;

  u16* wslot = stg + (w << 13);  // wave-private 16KB

  for (int t = 0; t <= TT; ++t) {
    const u16* Hp = hb + (size_t)((t + 3) & 3) * HSZ;
    u16* Hc = hb + (size_t)(t & 3) * HSZ;

    if (t < TT) {
      if (l == 0) {
        if (tid < BB) sids[tid] = idsT[t * BB + tid];
        __syncthreads();
      }
      // per-lane staging source pointers (4 row-groups x {x,h})
      const int kw = (w << 8) + lelem;
      const u16* hb0 = Hp + (size_t)l * BB * DD + kw;
      const u16 *px0, *px1, *px2, *px3;
      if (l == 0) {
        px0 = embb + (size_t)sids[lrow] * DD + kw;
        px1 = embb + (size_t)sids[16 + lrow] * DD + kw;
        px2 = embb + (size_t)sids[32 + lrow] * DD + kw;
        px3 = embb + (size_t)sids[48 + lrow] * DD + kw;
      } else {
        const u16* xb0 = Hp + (size_t)(l - 1) * BB * DD + kw;
        px0 = xb0 + (size_t)lrow * DD;
        px1 = xb0 + (size_t)(16 + lrow) * DD;
        px2 = xb0 + (size_t)(32 + lrow) * DD;
        px3 = xb0 + (size_t)(48 + lrow) * DD;
      }
      const u16* ph0 = hb0 + (size_t)lrow * DD;
      const u16* ph1 = hb0 + (size_t)(16 + lrow) * DD;
      const u16* ph2 = hb0 + (size_t)(32 + lrow) * DD;
      const u16* ph3 = hb0 + (size_t)(48 + lrow) * DD;

      // prologue: stage chunks 0,1 (8 GLs each)
#pragma unroll
      for (int c = 0; c < 2; ++c) {
        u16* d = wslot + (c << 12);
        GL(px0 + (c << 5), d);
        GL(px1 + (c << 5), d + 512);
        GL(px2 + (c << 5), d + 1024);
        GL(px3 + (c << 5), d + 1536);
        GL(ph0 + (c << 5), d + 2048);
        GL(ph1 + (c << 5), d + 2560);
        GL(ph2 + (c << 5), d + 3072);
        GL(ph3 + (c << 5), d + 3584);
      }

      f32x4 acc[2][4] = {{{0,0,0,0},{0,0,0,0},{0,0,0,0},{0,0,0,0}},
                         {{0,0,0,0},{0,0,0,0},{0,0,0,0},{0,0,0,0}}};
#pragma unroll
      for (int j = 0; j < 8; ++j) {
        if (j < 7) asm volatile("s_waitcnt vmcnt(8)" ::: "memory");
        else       asm volatile("s_waitcnt vmcnt(0)" ::: "memory");
        __builtin_amdgcn_sched_barrier(0);
        const u16* sb = wslot + ((j & 1) << 12);
        s16x8 ax0 = *(const s16x8*)(sb + fx);
        s16x8 ax1 = *(const s16x8*)(sb + 512 + fx);
        s16x8 ax2 = *(const s16x8*)(sb + 1024 + fx);
        s16x8 ax3 = *(const s16x8*)(sb + 1536 + fx);
        s16x8 ah0 = *(const s16x8*)(sb + 2048 + fx);
        s16x8 ah1 = *(const s16x8*)(sb + 2560 + fx);
        s16x8 ah2 = *(const s16x8*)(sb + 3072 + fx);
        s16x8 ah3 = *(const s16x8*)(sb + 3584 + fx);
        asm volatile("s_waitcnt lgkmcnt(0)" ::: "memory");
        __builtin_amdgcn_sched_barrier(0);
        if (j < 6) {  // refill same slot with chunk j+2 (reads done)
          u16* d = wslot + ((j & 1) << 12);
          const int co = (j + 2) << 5;
          GL(px0 + co, d);
          GL(px1 + co, d + 512);
          GL(px2 + co, d + 1024);
          GL(px3 + co, d + 1536);
          GL(ph0 + co, d + 2048);
          GL(ph1 + co, d + 2560);
          GL(ph2 + co, d + 3072);
          GL(ph3 + co, d + 3584);
        }
#pragma unroll
        for (int c = 0; c < 2; ++c) {
          acc[c][0] = MFMA(ax0, wx[c][j], acc[c][0]);
          acc[c][0] = MFMA(ah0, wh[c][j], acc[c][0]);
          acc[c][1] = MFMA(ax1, wx[c][j], acc[c][1]);
          acc[c][1] = MFMA(ah1, wh[c][j], acc[c][1]);
          acc[c][2] = MFMA(ax2, wx[c][j], acc[c][2]);
          acc[c][2] = MFMA(ah2, wh[c][j], acc[c][2]);
          acc[c][3] = MFMA(ax3, wx[c][j], acc[c][3]);
          acc[c][3] = MFMA(ah3, wh[c][j], acc[c][3]);
        }
      }

      __syncthreads();  // all waves done reading stg; part may overwrite
#pragma unroll
      for (int c = 0; c < 2; ++c)
#pragma unroll
        for (int mt = 0; mt < 4; ++mt)
#pragma unroll
          for (int i = 0; i < 4; ++i)
            part[((w << 6) + (mt << 4) + (q << 2) + i) * 36 + (c << 4) + lr] =
                acc[c][mt][i];
      __syncthreads();

      // 8-way K-combine + bias + tanh + mask + packed agent write-through store
      {
        f32x4 sum = {0, 0, 0, 0};
#pragma unroll
        for (int k2 = 0; k2 < 8; ++k2)
          sum += *(const f32x4*)&part[((k2 << 6) + rm) * 36 + rng];
        float h0 = tanhf(sum[0] + qb[0]);
        float h1 = tanhf(sum[1] + qb[1]);
        float h2 = tanhf(sum[2] + qb[2]);
        float h3 = tanhf(sum[3] + qb[3]);
        size_t idx = ((size_t)l * BB + rm) * DD + qcol;
        u64 pk = (u64)f2b(h0) | ((u64)f2b(h1) << 16) |
                 ((u64)f2b(h2) << 32) | ((u64)f2b(h3) << 48);
        u64 val = (t < qlen) ? pk : *(const u64*)(Hp + idx);
        __hip_atomic_store((u64*)(Hc + idx), val, __ATOMIC_RELAXED,
                           __HIP_MEMORY_SCOPE_AGENT);
      }
      asm volatile("s_waitcnt vmcnt(0)" ::: "memory");
    }
    __syncthreads();

    const int ep = t + 1;
    if (t < TT && tid == 0)
      __hip_atomic_store(&flags[bid << 5], ep, __ATOMIC_RELAXED,
                         __HIP_MEMORY_SCOPE_AGENT);

    // out-proj for step t-1 (Hp), overlapped with other blocks' arrivals
    if (t > 0) {
      const u16* h3p = Hp + (size_t)3 * BB * DD;
      const u16* hp = h3p + (size_t)opb * DD + (ln32 << 6);
      const u16* wp = WoT + (size_t)opv * DD + (ln32 << 6);
      float sacc = 0.f;
#pragma unroll
      for (int j = 0; j < 64; j += 8) {
        s16x8 hv8 = *(const s16x8*)(hp + j);
        s16x8 wv8 = *(const s16x8*)(wp + j);
#pragma unroll
        for (int e = 0; e < 8; ++e)
          sacc = fmaf(b2f((u16)hv8[e]), b2f((u16)wv8[e]), sacc);
      }
#pragma unroll
      for (int d = 16; d > 0; d >>= 1) sacc += __shfl_xor(sacc, d, 64);
      if (ln32 == 0)
        out[((size_t)opb * TT + (t - 1)) * VV + opv] = sacc + boutv;
    }

    if (t < TT) {
      for (;;) {
        int f = ep;
        if (lane < 32)
          f = __hip_atomic_load(&flags[fidx], __ATOMIC_RELAXED,
                                __HIP_MEMORY_SCOPE_AGENT);
        int ok = __all(f - ep >= 0);
        if (lane == 0) wok[w] = ok;
        __syncthreads();
        if (tid == 0)
          alldone = wok[0] & wok[1] & wok[2] & wok[3] &
                    wok[4] & wok[5] & wok[6] & wok[7];
        __syncthreads();
        if (alldone) break;
        __builtin_amdgcn_s_sleep(1);
      }
      if ((ep & 3) == 0 && tid == 0)
        __hip_atomic_load(&flags[0], __ATOMIC_ACQUIRE, __HIP_MEMORY_SCOPE_AGENT);
      __syncthreads();
    }
  }
}

extern "C" void kernel_launch(void* const* d_in, const int* in_sizes, int n_in,
                              void* d_out, int out_size, void* d_ws, size_t ws_size,
                              hipStream_t stream) {
  const int* ids = (const int*)d_in[0];
  const int* slen = (const int*)d_in[1];
  const float* emb = (const float*)d_in[2];
  const float* Wx = (const float*)d_in[3];
  const float* bx = (const float*)d_in[4];
  const float* Wh = (const float*)d_in[5];
  const float* bh = (const float*)d_in[6];
  const float* Wout = (const float*)d_in[7];
  const float* bout = (const float*)d_in[8];
  float* out = (float*)d_out;

  char* ws = (char*)d_ws;
  const size_t oW = (size_t)LL * DD * DD * 2;
  const size_t oWoT = (size_t)VV * DD * 2;
  const size_t oEmb = (size_t)VV * DD * 2;
  const size_t oHb = (size_t)LL * BB * DD * 2;
  u16* Wxb = (u16*)ws;
  u16* Whb = (u16*)(ws + oW);
  u16* WoT = (u16*)(ws + 2 * oW);
  u16* embb = (u16*)(ws + 2 * oW + oWoT);
  u16* hb = (u16*)(ws + 2 * oW + oWoT + oEmb);          // 4-ring state
  int* flags = (int*)(ws + 2 * oW + oWoT + oEmb + 4 * oHb);
  int* idsT = (int*)(ws + 2 * oW + oWoT + oEmb + 4 * oHb + 32768);

  hipMemsetAsync(ws + 2 * oW + oWoT + oEmb, 0, 4 * oHb + 32768, stream);

  const size_t n4 = (size_t)LL * DD * DD / 4;
  convert_w<<<dim3(4096), dim3(256), 0, stream>>>(Wx, Wxb, n4);
  convert_w<<<dim3(4096), dim3(256), 0, stream>>>(Wh, Whb, n4);
  convert_w<<<dim3(128), dim3(256), 0, stream>>>(emb, embb, (size_t)VV * DD / 4);
  convert_woT<<<dim3(512), dim3(256), 0, stream>>>(Wout, WoT);
  transpose_ids<<<dim3(128), dim3(256), 0, stream>>>(ids, idsT);

  void* kp[12];
  kp[0] = (void*)&idsT; kp[1] = (void*)&slen;
  kp[2] = (void*)&bx;   kp[3] = (void*)&bh;   kp[4] = (void*)&embb;
  kp[5] = (void*)&Wxb;  kp[6] = (void*)&Whb;  kp[7] = (void*)&WoT;
  kp[8] = (void*)&bout; kp[9] = (void*)&hb;   kp[10] = (void*)&out;
  kp[11] = (void*)&flags;
  hipLaunchCooperativeKernel((const void*)persist, dim3(256), dim3(512), kp, 0, stream);
}